// Round 1
// baseline (149.536 us; speedup 1.0000x reference)
//
#include <hip/hip_runtime.h>
#include <math.h>

#define NP 8192
#define NF 16384
#define GQ 4

// ---------------------------------------------------------------------------
// K0: face centers in f64 + |c|^2, exactly mirroring np: c = (v0+v1+v2)/3
// ---------------------------------------------------------------------------
__global__ __launch_bounds__(256) void k_centers(const float* __restrict__ mV,
                                                 const int* __restrict__ mF,
                                                 double* __restrict__ ctr) {
    int f = blockIdx.x * 256 + threadIdx.x;
    if (f >= NF) return;
    int i0 = mF[3*f+0], i1 = mF[3*f+1], i2 = mF[3*f+2];
    double cx = ((double)mV[3*i0+0] + (double)mV[3*i1+0] + (double)mV[3*i2+0]) / 3.0;
    double cy = ((double)mV[3*i0+1] + (double)mV[3*i1+1] + (double)mV[3*i2+1]) / 3.0;
    double cz = ((double)mV[3*i0+2] + (double)mV[3*i1+2] + (double)mV[3*i2+2]) / 3.0;
    ctr[4*f+0] = cx; ctr[4*f+1] = cy; ctr[4*f+2] = cz;
    ctr[4*f+3] = cx*cx + cy*cy + cz*cz;
}

// ---------------------------------------------------------------------------
// K1: brute-force 1-NN, d2 = (|q|^2 - 2 q.c) + |c|^2, argmin w/ lowest-index
// tie-break (jnp.argmin semantics). One block handles GQ query points.
// ---------------------------------------------------------------------------
__global__ __launch_bounds__(256) void k_knn(const float* __restrict__ qV,
                                             const double* __restrict__ ctr,
                                             float* __restrict__ out,
                                             int* __restrict__ fidx_ws,
                                             int* __restrict__ valid_ws) {
    int pbase = blockIdx.x * GQ;
    double qx[GQ], qy[GQ], qz[GQ], qq[GQ];
    #pragma unroll
    for (int g = 0; g < GQ; ++g) {
        int p = pbase + g;
        qx[g] = (double)qV[3*p+0];
        qy[g] = (double)qV[3*p+1];
        qz[g] = (double)qV[3*p+2];
        qq[g] = qx[g]*qx[g] + qy[g]*qy[g] + qz[g]*qz[g];
    }
    double best[GQ]; int bidx[GQ];
    #pragma unroll
    for (int g = 0; g < GQ; ++g) { best[g] = 1e300; bidx[g] = 0x7fffffff; }

    for (int f = threadIdx.x; f < NF; f += 256) {
        double cx = ctr[4*f+0], cy = ctr[4*f+1], cz = ctr[4*f+2], cc = ctr[4*f+3];
        #pragma unroll
        for (int g = 0; g < GQ; ++g) {
            double dot = qx[g]*cx + qy[g]*cy + qz[g]*cz;
            double d2 = (qq[g] - 2.0*dot) + cc;
            if (d2 < best[g] || (d2 == best[g] && f < bidx[g])) { best[g] = d2; bidx[g] = f; }
        }
    }
    // wave (64-lane) reduction
    #pragma unroll
    for (int off = 32; off > 0; off >>= 1) {
        #pragma unroll
        for (int g = 0; g < GQ; ++g) {
            double ov = __shfl_down(best[g], off);
            int    oi = __shfl_down(bidx[g], off);
            if (ov < best[g] || (ov == best[g] && oi < bidx[g])) { best[g] = ov; bidx[g] = oi; }
        }
    }
    __shared__ double sv[4][GQ];
    __shared__ int    si[4][GQ];
    int wid = threadIdx.x >> 6, lane = threadIdx.x & 63;
    if (lane == 0) {
        #pragma unroll
        for (int g = 0; g < GQ; ++g) { sv[wid][g] = best[g]; si[wid][g] = bidx[g]; }
    }
    __syncthreads();
    if (threadIdx.x == 0) {
        for (int g = 0; g < GQ; ++g) {
            double bv = sv[0][g]; int bi = si[0][g];
            for (int w2 = 1; w2 < 4; ++w2) {
                double ov = sv[w2][g]; int oi = si[w2][g];
                if (ov < bv || (ov == bv && oi < bi)) { bv = ov; bi = oi; }
            }
            int p = pbase + g;
            int outlier = (bv > 0.1) ? 1 : 0;
            fidx_ws[p]  = bi;
            valid_ws[p] = 1 - outlier;
            out[p]          = (float)bi;              // output 0: spt_fidx
            out[3*NP + p]   = outlier ? 1.0f : 0.0f;  // output 2: outlier_mask
        }
    }
}

// ---------------------------------------------------------------------------
// K2: denom = max(#valid, 1)
// ---------------------------------------------------------------------------
__global__ __launch_bounds__(256) void k_denom(const int* __restrict__ valid_ws,
                                               double* __restrict__ denom) {
    __shared__ int s[256];
    int acc = 0;
    for (int i = threadIdx.x; i < NP; i += 256) acc += valid_ws[i];
    s[threadIdx.x] = acc;
    __syncthreads();
    for (int off = 128; off > 0; off >>= 1) {
        if (threadIdx.x < off) s[threadIdx.x] += s[threadIdx.x + off];
        __syncthreads();
    }
    if (threadIdx.x == 0) {
        double d = (double)s[0];
        denom[0] = d > 1.0 ? d : 1.0;
    }
}

// ---------------------------------------------------------------------------
// K3: per-point 2x50-step Adagrad on delta (analytic grad == jax.grad), f64.
// ---------------------------------------------------------------------------
__global__ __launch_bounds__(256) void k_opt(const float* __restrict__ qV,
                                             const float* __restrict__ qN,
                                             const float* __restrict__ mV,
                                             const int* __restrict__ mF,
                                             const float* __restrict__ mN,
                                             const int* __restrict__ fidx_ws,
                                             const int* __restrict__ valid_ws,
                                             const double* __restrict__ denomp,
                                             float* __restrict__ out) {
    int p = blockIdx.x * 256 + threadIdx.x;
    if (p >= NP) return;
    const float third = (float)(1.0/3.0);
    if (!valid_ws[p]) {            // outlier: keeps init barycentric coords
        out[NP + 2*p + 0] = third;
        out[NP + 2*p + 1] = third;
        return;
    }
    double denom = denomp[0];
    int f = fidx_ws[p];
    int i0 = mF[3*f+0], i1 = mF[3*f+1], i2 = mF[3*f+2];

    double V0x = mV[3*i0+0], V0y = mV[3*i0+1], V0z = mV[3*i0+2];
    double V1x = mV[3*i1+0], V1y = mV[3*i1+1], V1z = mV[3*i1+2];
    double V2x = mV[3*i2+0], V2y = mV[3*i2+1], V2z = mV[3*i2+2];
    double N0x = mN[3*i0+0], N0y = mN[3*i0+1], N0z = mN[3*i0+2];
    double N1x = mN[3*i1+0], N1y = mN[3*i1+1], N1z = mN[3*i1+2];
    double N2x = mN[3*i2+0], N2y = mN[3*i2+1], N2z = mN[3*i2+2];
    double qx  = qV[3*p+0],  qy  = qV[3*p+1],  qz  = qV[3*p+2];
    double qnx = qN[3*p+0],  qny = qN[3*p+1],  qnz = qN[3*p+2];

    double Eux = V0x - V2x, Euy = V0y - V2y, Euz = V0z - V2z;  // dcV/du
    double Ewx = V1x - V2x, Ewy = V1y - V2y, Ewz = V1z - V2z;  // dcV/dw
    double Fux = N0x - N2x, Fuy = N0y - N2y, Fuz = N0z - N2z;  // dn_raw/du
    double Fwx = N1x - N2x, Fwy = N1y - N2y, Fwz = N1z - N2z;  // dn_raw/dw

    double u = 1.0/3.0, w = 1.0/3.0;
    double alpha = 1.0;
    for (int outer = 0; outer < 2; ++outer) {
        double du = 0.0, dw = 0.0, su = 0.0, sw = 0.0;
        for (int it = 0; it < 50; ++it) {
            double uu = u + du, ww = w + dw, b2 = 1.0 - uu - ww;
            // position term
            double cvx = uu*V0x + ww*V1x + b2*V2x;
            double cvy = uu*V0y + ww*V1y + b2*V2y;
            double cvz = uu*V0z + ww*V1z + b2*V2z;
            double rvx = cvx - qx, rvy = cvy - qy, rvz = cvz - qz;
            double Lv = sqrt(rvx*rvx + rvy*rvy + rvz*rvz);
            double gu = (rvx*Eux + rvy*Euy + rvz*Euz) / Lv;
            double gw = (rvx*Ewx + rvy*Ewy + rvz*Ewz) / Lv;
            // normal term
            double nx = uu*N0x + ww*N1x + b2*N2x;
            double ny = uu*N0y + ww*N1y + b2*N2y;
            double nz = uu*N0z + ww*N1z + b2*N2z;
            double m2 = nx*nx + ny*ny + nz*nz;
            double m  = sqrt(m2);
            double mm = (m > 1e-12) ? m : 1e-12;  // F.normalize eps
            double inv = 1.0 / mm;
            double hx = nx*inv, hy = ny*inv, hz = nz*inv;
            double rnx = hx - qnx, rny = hy - qny, rnz = hz - qnz;
            double Ln = sqrt(rnx*rnx + rny*rny + rnz*rnz);
            double A_u = rnx*Fux + rny*Fuy + rnz*Fuz;
            double A_w = rnx*Fwx + rny*Fwy + rnz*Fwz;
            double B   = rnx*nx + rny*ny + rnz*nz;
            double C_u = nx*Fux + ny*Fuy + nz*Fuz;
            double C_w = nx*Fwx + ny*Fwy + nz*Fwz;
            double gnu, gnw;
            if (m > 1e-12) {
                gnu = (A_u*inv - B*C_u*inv*inv/m) / Ln;
                gnw = (A_w*inv - B*C_w*inv*inv/m) / Ln;
            } else {
                gnu = (A_u*inv) / Ln;
                gnw = (A_w*inv) / Ln;
            }
            gu = (gu + 0.01*gnu) / denom;   // mask=1, masked-mean scaling
            gw = (gw + 0.01*gnw) / denom;
            // Adagrad(lr=0.2, lr_decay=0.1)
            su += gu*gu; sw += gw*gw;
            double clr = 0.2 / (1.0 + (double)it * 0.1);
            du -= clr * gu / (sqrt(su) + 1e-10);
            dw -= clr * gw / (sqrt(sw) + 1e-10);
        }
        u += du * alpha; w += dw * alpha;
        alpha *= 0.5;
    }
    out[NP + 2*p + 0] = (float)u;
    out[NP + 2*p + 1] = (float)w;
}

// ---------------------------------------------------------------------------
extern "C" void kernel_launch(void* const* d_in, const int* in_sizes, int n_in,
                              void* d_out, int out_size, void* d_ws, size_t ws_size,
                              hipStream_t stream) {
    const float* qV = (const float*)d_in[0];   // query_V [1,8192,3]
    const float* qN = (const float*)d_in[1];   // query_N [1,8192,3]
    const float* mV = (const float*)d_in[2];   // mesh_V  [16384,3]
    const int*   mF = (const int*)d_in[3];     // mesh_F  [16384,3] int32
    const float* mN = (const float*)d_in[4];   // mesh_N  [16384,3]
    float* out = (float*)d_out;                // fidx | vw | outlier_mask

    double* ctr      = (double*)d_ws;          // NF*4 doubles (cx,cy,cz,|c|^2)
    double* denom    = ctr + (size_t)NF*4;     // 1 double
    int*    fidx_ws  = (int*)(denom + 1);      // NP ints
    int*    valid_ws = fidx_ws + NP;           // NP ints

    hipLaunchKernelGGL(k_centers, dim3(NF/256), dim3(256), 0, stream, mV, mF, ctr);
    hipLaunchKernelGGL(k_knn,     dim3(NP/GQ),  dim3(256), 0, stream, qV, ctr, out, fidx_ws, valid_ws);
    hipLaunchKernelGGL(k_denom,   dim3(1),      dim3(256), 0, stream, valid_ws, denom);
    hipLaunchKernelGGL(k_opt,     dim3(NP/256), dim3(256), 0, stream,
                       qV, qN, mV, mF, mN, fidx_ws, valid_ws, denom, out);
}

// Round 2
// 133.146 us; speedup vs baseline: 1.1231x; 1.1231x over previous
//
#include <hip/hip_runtime.h>
#include <math.h>

#define NP 8192
#define NF 16384
#define GQ 8

// ---------------------------------------------------------------------------
// K0: face centers in f64 + |c|^2, exactly mirroring np: c = (v0+v1+v2)/3
// ---------------------------------------------------------------------------
__global__ __launch_bounds__(256) void k_centers(const float* __restrict__ mV,
                                                 const int* __restrict__ mF,
                                                 double* __restrict__ ctr) {
    int f = blockIdx.x * 256 + threadIdx.x;
    if (f >= NF) return;
    int i0 = mF[3*f+0], i1 = mF[3*f+1], i2 = mF[3*f+2];
    double cx = ((double)mV[3*i0+0] + (double)mV[3*i1+0] + (double)mV[3*i2+0]) / 3.0;
    double cy = ((double)mV[3*i0+1] + (double)mV[3*i1+1] + (double)mV[3*i2+1]) / 3.0;
    double cz = ((double)mV[3*i0+2] + (double)mV[3*i1+2] + (double)mV[3*i2+2]) / 3.0;
    ctr[4*f+0] = cx; ctr[4*f+1] = cy; ctr[4*f+2] = cz;
    ctr[4*f+3] = cx*cx + cy*cy + cz*cz;
}

// ---------------------------------------------------------------------------
// K1: brute-force 1-NN, d2 = (|q|^2 - 2 q.c) + |c|^2, argmin w/ lowest-index
// tie-break (jnp.argmin semantics). One block handles GQ query points.
// Within a thread the face index strictly increases, so "<" suffices; the
// cross-thread/wave reduction stays lexicographic (value, idx) — exact.
// ---------------------------------------------------------------------------
__global__ __launch_bounds__(256) void k_knn(const float* __restrict__ qV,
                                             const double* __restrict__ ctr,
                                             float* __restrict__ out,
                                             int* __restrict__ fidx_ws,
                                             int* __restrict__ valid_ws) {
    int pbase = blockIdx.x * GQ;
    double qx[GQ], qy[GQ], qz[GQ], qq[GQ];
    #pragma unroll
    for (int g = 0; g < GQ; ++g) {
        int p = pbase + g;
        qx[g] = (double)qV[3*p+0];
        qy[g] = (double)qV[3*p+1];
        qz[g] = (double)qV[3*p+2];
        qq[g] = qx[g]*qx[g] + qy[g]*qy[g] + qz[g]*qz[g];
    }
    double best[GQ]; int bidx[GQ];
    #pragma unroll
    for (int g = 0; g < GQ; ++g) { best[g] = 1e300; bidx[g] = 0x7fffffff; }

    const double4* ctr4 = (const double4*)ctr;
    #pragma unroll 2
    for (int f = threadIdx.x; f < NF; f += 256) {
        double4 c = ctr4[f];
        #pragma unroll
        for (int g = 0; g < GQ; ++g) {
            double dot = qx[g]*c.x + qy[g]*c.y + qz[g]*c.z;
            double d2 = (qq[g] - 2.0*dot) + c.w;
            if (d2 < best[g]) { best[g] = d2; bidx[g] = f; }
        }
    }
    // wave (64-lane) reduction, lexicographic (value, idx)
    #pragma unroll
    for (int off = 32; off > 0; off >>= 1) {
        #pragma unroll
        for (int g = 0; g < GQ; ++g) {
            double ov = __shfl_down(best[g], off);
            int    oi = __shfl_down(bidx[g], off);
            if (ov < best[g] || (ov == best[g] && oi < bidx[g])) { best[g] = ov; bidx[g] = oi; }
        }
    }
    __shared__ double sv[4][GQ];
    __shared__ int    si[4][GQ];
    int wid = threadIdx.x >> 6, lane = threadIdx.x & 63;
    if (lane == 0) {
        #pragma unroll
        for (int g = 0; g < GQ; ++g) { sv[wid][g] = best[g]; si[wid][g] = bidx[g]; }
    }
    __syncthreads();
    if (threadIdx.x == 0) {
        for (int g = 0; g < GQ; ++g) {
            double bv = sv[0][g]; int bi = si[0][g];
            for (int w2 = 1; w2 < 4; ++w2) {
                double ov = sv[w2][g]; int oi = si[w2][g];
                if (ov < bv || (ov == bv && oi < bi)) { bv = ov; bi = oi; }
            }
            int p = pbase + g;
            int outlier = (bv > 0.1) ? 1 : 0;
            fidx_ws[p]  = bi;
            valid_ws[p] = 1 - outlier;
            out[p]          = (float)bi;              // output 0: spt_fidx
            out[3*NP + p]   = outlier ? 1.0f : 0.0f;  // output 2: outlier_mask
        }
    }
}

// ---------------------------------------------------------------------------
// K2: denom = max(#valid, 1)
// ---------------------------------------------------------------------------
__global__ __launch_bounds__(256) void k_denom(const int* __restrict__ valid_ws,
                                               double* __restrict__ denom) {
    __shared__ int s[256];
    int acc = 0;
    for (int i = threadIdx.x; i < NP; i += 256) acc += valid_ws[i];
    s[threadIdx.x] = acc;
    __syncthreads();
    for (int off = 128; off > 0; off >>= 1) {
        if (threadIdx.x < off) s[threadIdx.x] += s[threadIdx.x + off];
        __syncthreads();
    }
    if (threadIdx.x == 0) {
        double d = (double)s[0];
        denom[0] = d > 1.0 ? d : 1.0;
    }
}

// ---------------------------------------------------------------------------
// K3: per-point 2x50-step Adagrad on delta (analytic grad == jax.grad), f64.
// KEPT BIT-IDENTICAL to the passing round-1 version (chaotic trajectory;
// do not perturb rounding).
// ---------------------------------------------------------------------------
__global__ __launch_bounds__(256) void k_opt(const float* __restrict__ qV,
                                             const float* __restrict__ qN,
                                             const float* __restrict__ mV,
                                             const int* __restrict__ mF,
                                             const float* __restrict__ mN,
                                             const int* __restrict__ fidx_ws,
                                             const int* __restrict__ valid_ws,
                                             const double* __restrict__ denomp,
                                             float* __restrict__ out) {
    int p = blockIdx.x * 256 + threadIdx.x;
    if (p >= NP) return;
    const float third = (float)(1.0/3.0);
    if (!valid_ws[p]) {            // outlier: keeps init barycentric coords
        out[NP + 2*p + 0] = third;
        out[NP + 2*p + 1] = third;
        return;
    }
    double denom = denomp[0];
    int f = fidx_ws[p];
    int i0 = mF[3*f+0], i1 = mF[3*f+1], i2 = mF[3*f+2];

    double V0x = mV[3*i0+0], V0y = mV[3*i0+1], V0z = mV[3*i0+2];
    double V1x = mV[3*i1+0], V1y = mV[3*i1+1], V1z = mV[3*i1+2];
    double V2x = mV[3*i2+0], V2y = mV[3*i2+1], V2z = mV[3*i2+2];
    double N0x = mN[3*i0+0], N0y = mN[3*i0+1], N0z = mN[3*i0+2];
    double N1x = mN[3*i1+0], N1y = mN[3*i1+1], N1z = mN[3*i1+2];
    double N2x = mN[3*i2+0], N2y = mN[3*i2+1], N2z = mN[3*i2+2];
    double qx  = qV[3*p+0],  qy  = qV[3*p+1],  qz  = qV[3*p+2];
    double qnx = qN[3*p+0],  qny = qN[3*p+1],  qnz = qN[3*p+2];

    double Eux = V0x - V2x, Euy = V0y - V2y, Euz = V0z - V2z;  // dcV/du
    double Ewx = V1x - V2x, Ewy = V1y - V2y, Ewz = V1z - V2z;  // dcV/dw
    double Fux = N0x - N2x, Fuy = N0y - N2y, Fuz = N0z - N2z;  // dn_raw/du
    double Fwx = N1x - N2x, Fwy = N1y - N2y, Fwz = N1z - N2z;  // dn_raw/dw

    double u = 1.0/3.0, w = 1.0/3.0;
    double alpha = 1.0;
    for (int outer = 0; outer < 2; ++outer) {
        double du = 0.0, dw = 0.0, su = 0.0, sw = 0.0;
        for (int it = 0; it < 50; ++it) {
            double uu = u + du, ww = w + dw, b2 = 1.0 - uu - ww;
            // position term
            double cvx = uu*V0x + ww*V1x + b2*V2x;
            double cvy = uu*V0y + ww*V1y + b2*V2y;
            double cvz = uu*V0z + ww*V1z + b2*V2z;
            double rvx = cvx - qx, rvy = cvy - qy, rvz = cvz - qz;
            double Lv = sqrt(rvx*rvx + rvy*rvy + rvz*rvz);
            double gu = (rvx*Eux + rvy*Euy + rvz*Euz) / Lv;
            double gw = (rvx*Ewx + rvy*Ewy + rvz*Ewz) / Lv;
            // normal term
            double nx = uu*N0x + ww*N1x + b2*N2x;
            double ny = uu*N0y + ww*N1y + b2*N2y;
            double nz = uu*N0z + ww*N1z + b2*N2z;
            double m2 = nx*nx + ny*ny + nz*nz;
            double m  = sqrt(m2);
            double mm = (m > 1e-12) ? m : 1e-12;  // F.normalize eps
            double inv = 1.0 / mm;
            double hx = nx*inv, hy = ny*inv, hz = nz*inv;
            double rnx = hx - qnx, rny = hy - qny, rnz = hz - qnz;
            double Ln = sqrt(rnx*rnx + rny*rny + rnz*rnz);
            double A_u = rnx*Fux + rny*Fuy + rnz*Fuz;
            double A_w = rnx*Fwx + rny*Fwy + rnz*Fwz;
            double B   = rnx*nx + rny*ny + rnz*nz;
            double C_u = nx*Fux + ny*Fuy + nz*Fuz;
            double C_w = nx*Fwx + ny*Fwy + nz*Fwz;
            double gnu, gnw;
            if (m > 1e-12) {
                gnu = (A_u*inv - B*C_u*inv*inv/m) / Ln;
                gnw = (A_w*inv - B*C_w*inv*inv/m) / Ln;
            } else {
                gnu = (A_u*inv) / Ln;
                gnw = (A_w*inv) / Ln;
            }
            gu = (gu + 0.01*gnu) / denom;   // mask=1, masked-mean scaling
            gw = (gw + 0.01*gnw) / denom;
            // Adagrad(lr=0.2, lr_decay=0.1)
            su += gu*gu; sw += gw*gw;
            double clr = 0.2 / (1.0 + (double)it * 0.1);
            du -= clr * gu / (sqrt(su) + 1e-10);
            dw -= clr * gw / (sqrt(sw) + 1e-10);
        }
        u += du * alpha; w += dw * alpha;
        alpha *= 0.5;
    }
    out[NP + 2*p + 0] = (float)u;
    out[NP + 2*p + 1] = (float)w;
}

// ---------------------------------------------------------------------------
extern "C" void kernel_launch(void* const* d_in, const int* in_sizes, int n_in,
                              void* d_out, int out_size, void* d_ws, size_t ws_size,
                              hipStream_t stream) {
    const float* qV = (const float*)d_in[0];   // query_V [1,8192,3]
    const float* qN = (const float*)d_in[1];   // query_N [1,8192,3]
    const float* mV = (const float*)d_in[2];   // mesh_V  [16384,3]
    const int*   mF = (const int*)d_in[3];     // mesh_F  [16384,3] int32
    const float* mN = (const float*)d_in[4];   // mesh_N  [16384,3]
    float* out = (float*)d_out;                // fidx | vw | outlier_mask

    double* ctr      = (double*)d_ws;          // NF*4 doubles (cx,cy,cz,|c|^2)
    double* denom    = ctr + (size_t)NF*4;     // 1 double
    int*    fidx_ws  = (int*)(denom + 1);      // NP ints
    int*    valid_ws = fidx_ws + NP;           // NP ints

    hipLaunchKernelGGL(k_centers, dim3(NF/256), dim3(256), 0, stream, mV, mF, ctr);
    hipLaunchKernelGGL(k_knn,     dim3(NP/GQ),  dim3(256), 0, stream, qV, ctr, out, fidx_ws, valid_ws);
    hipLaunchKernelGGL(k_denom,   dim3(1),      dim3(256), 0, stream, valid_ws, denom);
    hipLaunchKernelGGL(k_opt,     dim3(NP/256), dim3(256), 0, stream,
                       qV, qN, mV, mF, mN, fidx_ws, valid_ws, denom, out);
}

// Round 3
// 111.237 us; speedup vs baseline: 1.3443x; 1.1970x over previous
//
#include <hip/hip_runtime.h>
#include <math.h>

#define NP 8192
#define NF 16384
#define GQ 8

// ---------------------------------------------------------------------------
// K0: face centers in f64 + |c|^2 (np: c=(v0+v1+v2)/3), plus Adagrad clr table
// ---------------------------------------------------------------------------
__global__ __launch_bounds__(256) void k_centers(const float* __restrict__ mV,
                                                 const int* __restrict__ mF,
                                                 double* __restrict__ ctr,
                                                 double* __restrict__ clrtab) {
    if (blockIdx.x == 0 && threadIdx.x < 50) {
        clrtab[threadIdx.x] = 0.2 / (1.0 + (double)threadIdx.x * 0.1);
    }
    int f = blockIdx.x * 256 + threadIdx.x;
    if (f >= NF) return;
    int i0 = mF[3*f+0], i1 = mF[3*f+1], i2 = mF[3*f+2];
    double cx = ((double)mV[3*i0+0] + (double)mV[3*i1+0] + (double)mV[3*i2+0]) / 3.0;
    double cy = ((double)mV[3*i0+1] + (double)mV[3*i1+1] + (double)mV[3*i2+1]) / 3.0;
    double cz = ((double)mV[3*i0+2] + (double)mV[3*i1+2] + (double)mV[3*i2+2]) / 3.0;
    ctr[4*f+0] = cx; ctr[4*f+1] = cy; ctr[4*f+2] = cz;
    ctr[4*f+3] = cx*cx + cy*cy + cz*cz;
}

// ---------------------------------------------------------------------------
// K1: brute-force 1-NN. Per-pair key = |c|^2 - 2 q.c (monotone in d2, the
// constant |q|^2 dropped). Winner's true d2 recomputed with np's exact
// association (qq - 2 dot) + cc for the outlier test. Lexicographic (key,idx)
// reduction preserves jnp.argmin first-index tie-break.
// ---------------------------------------------------------------------------
__global__ __launch_bounds__(256) void k_knn(const float* __restrict__ qV,
                                             const double* __restrict__ ctr,
                                             float* __restrict__ out,
                                             int* __restrict__ fidx_ws,
                                             int* __restrict__ valid_ws) {
    int pbase = blockIdx.x * GQ;
    double qx[GQ], qy[GQ], qz[GQ];
    #pragma unroll
    for (int g = 0; g < GQ; ++g) {
        int p = pbase + g;
        qx[g] = (double)qV[3*p+0];
        qy[g] = (double)qV[3*p+1];
        qz[g] = (double)qV[3*p+2];
    }
    double best[GQ]; int bidx[GQ];
    #pragma unroll
    for (int g = 0; g < GQ; ++g) { best[g] = 1e300; bidx[g] = 0x7fffffff; }

    const double4* ctr4 = (const double4*)ctr;
    #pragma unroll 2
    for (int f = threadIdx.x; f < NF; f += 256) {
        double4 c = ctr4[f];
        #pragma unroll
        for (int g = 0; g < GQ; ++g) {
            double dot = qx[g]*c.x + qy[g]*c.y + qz[g]*c.z;
            double key = c.w - 2.0*dot;
            if (key < best[g]) { best[g] = key; bidx[g] = f; }
        }
    }
    // wave (64-lane) reduction, lexicographic (key, idx)
    #pragma unroll
    for (int off = 32; off > 0; off >>= 1) {
        #pragma unroll
        for (int g = 0; g < GQ; ++g) {
            double ov = __shfl_down(best[g], off);
            int    oi = __shfl_down(bidx[g], off);
            if (ov < best[g] || (ov == best[g] && oi < bidx[g])) { best[g] = ov; bidx[g] = oi; }
        }
    }
    __shared__ double sv[4][GQ];
    __shared__ int    si[4][GQ];
    int wid = threadIdx.x >> 6, lane = threadIdx.x & 63;
    if (lane == 0) {
        #pragma unroll
        for (int g = 0; g < GQ; ++g) { sv[wid][g] = best[g]; si[wid][g] = bidx[g]; }
    }
    __syncthreads();
    if (threadIdx.x == 0) {
        for (int g = 0; g < GQ; ++g) {
            double bv = sv[0][g]; int bi = si[0][g];
            for (int w2 = 1; w2 < 4; ++w2) {
                double ov = sv[w2][g]; int oi = si[w2][g];
                if (ov < bv || (ov == bv && oi < bi)) { bv = ov; bi = oi; }
            }
            int p = pbase + g;
            // exact np d2 for the winning face
            double4 c = ctr4[bi];
            double dot = qx[g]*c.x + qy[g]*c.y + qz[g]*c.z;
            double qq  = qx[g]*qx[g] + qy[g]*qy[g] + qz[g]*qz[g];
            double d2  = (qq - 2.0*dot) + c.w;
            int outlier = (d2 > 0.1) ? 1 : 0;
            fidx_ws[p]  = bi;
            valid_ws[p] = 1 - outlier;
            out[p]          = (float)bi;              // output 0: spt_fidx
            out[3*NP + p]   = outlier ? 1.0f : 0.0f;  // output 2: outlier_mask
        }
    }
}

// ---------------------------------------------------------------------------
// K2: denom = max(#valid, 1)
// ---------------------------------------------------------------------------
__global__ __launch_bounds__(256) void k_denom(const int* __restrict__ valid_ws,
                                               double* __restrict__ denom) {
    __shared__ int s[256];
    int acc = 0;
    for (int i = threadIdx.x; i < NP; i += 256) acc += valid_ws[i];
    s[threadIdx.x] = acc;
    __syncthreads();
    for (int off = 128; off > 0; off >>= 1) {
        if (threadIdx.x < off) s[threadIdx.x] += s[threadIdx.x + off];
        __syncthreads();
    }
    if (threadIdx.x == 0) {
        double d = (double)s[0];
        denom[0] = d > 1.0 ? d : 1.0;
    }
}

// ---------------------------------------------------------------------------
// K3: per-point 2x50-step Adagrad, f64 throughout, div-minimized:
//   - residual refactor: cv-q = uu*Eu + ww*Ew + (V2-q); n = uu*Fu + ww*Fw + N2
//   - one reciprocal each for 1/Lv, 1/m, 1/Ln; 1/denom hoisted; clr from table
// All changes are f64 association-level (~1 ulp) — trajectory class unchanged.
// ---------------------------------------------------------------------------
__global__ __launch_bounds__(256) void k_opt(const float* __restrict__ qV,
                                             const float* __restrict__ qN,
                                             const float* __restrict__ mV,
                                             const int* __restrict__ mF,
                                             const float* __restrict__ mN,
                                             const int* __restrict__ fidx_ws,
                                             const int* __restrict__ valid_ws,
                                             const double* __restrict__ denomp,
                                             const double* __restrict__ clrtab,
                                             float* __restrict__ out) {
    int p = blockIdx.x * 256 + threadIdx.x;
    if (p >= NP) return;
    const float third = (float)(1.0/3.0);
    if (!valid_ws[p]) {            // outlier: keeps init barycentric coords
        out[NP + 2*p + 0] = third;
        out[NP + 2*p + 1] = third;
        return;
    }
    double inv_denom = 1.0 / denomp[0];
    int f = fidx_ws[p];
    int i0 = mF[3*f+0], i1 = mF[3*f+1], i2 = mF[3*f+2];

    double V0x = mV[3*i0+0], V0y = mV[3*i0+1], V0z = mV[3*i0+2];
    double V1x = mV[3*i1+0], V1y = mV[3*i1+1], V1z = mV[3*i1+2];
    double V2x = mV[3*i2+0], V2y = mV[3*i2+1], V2z = mV[3*i2+2];
    double N0x = mN[3*i0+0], N0y = mN[3*i0+1], N0z = mN[3*i0+2];
    double N1x = mN[3*i1+0], N1y = mN[3*i1+1], N1z = mN[3*i1+2];
    double N2x = mN[3*i2+0], N2y = mN[3*i2+1], N2z = mN[3*i2+2];
    double qx  = qV[3*p+0],  qy  = qV[3*p+1],  qz  = qV[3*p+2];
    double qnx = qN[3*p+0],  qny = qN[3*p+1],  qnz = qN[3*p+2];

    double Eux = V0x - V2x, Euy = V0y - V2y, Euz = V0z - V2z;  // dcV/du
    double Ewx = V1x - V2x, Ewy = V1y - V2y, Ewz = V1z - V2z;  // dcV/dw
    double Fux = N0x - N2x, Fuy = N0y - N2y, Fuz = N0z - N2z;  // dn_raw/du
    double Fwx = N1x - N2x, Fwy = N1y - N2y, Fwz = N1z - N2z;  // dn_raw/dw
    double Kx  = V2x - qx,  Ky  = V2y - qy,  Kz  = V2z - qz;   // cv - q at uu=ww=0

    double u = 1.0/3.0, w = 1.0/3.0;
    double alpha = 1.0;
    for (int outer = 0; outer < 2; ++outer) {
        double du = 0.0, dw = 0.0, su = 0.0, sw = 0.0;
        for (int it = 0; it < 50; ++it) {
            double uu = u + du, ww = w + dw;
            // position term: rv = cv - q = uu*Eu + ww*Ew + K
            double rvx = uu*Eux + ww*Ewx + Kx;
            double rvy = uu*Euy + ww*Ewy + Ky;
            double rvz = uu*Euz + ww*Ewz + Kz;
            double Lv = sqrt(rvx*rvx + rvy*rvy + rvz*rvz);
            double invLv = 1.0 / Lv;
            double gu = (rvx*Eux + rvy*Euy + rvz*Euz) * invLv;
            double gw = (rvx*Ewx + rvy*Ewy + rvz*Ewz) * invLv;
            // normal term: n = uu*Fu + ww*Fw + N2
            double nx = uu*Fux + ww*Fwx + N2x;
            double ny = uu*Fuy + ww*Fwy + N2y;
            double nz = uu*Fuz + ww*Fwz + N2z;
            double m2 = nx*nx + ny*ny + nz*nz;
            double m  = sqrt(m2);
            double mm = (m > 1e-12) ? m : 1e-12;  // F.normalize eps
            double inv = 1.0 / mm;
            double hx = nx*inv, hy = ny*inv, hz = nz*inv;
            double rnx = hx - qnx, rny = hy - qny, rnz = hz - qnz;
            double Ln = sqrt(rnx*rnx + rny*rny + rnz*rnz);
            double invLn = 1.0 / Ln;
            double A_u = rnx*Fux + rny*Fuy + rnz*Fuz;
            double A_w = rnx*Fwx + rny*Fwy + rnz*Fwz;
            double B   = rnx*nx + rny*ny + rnz*nz;
            double C_u = nx*Fux + ny*Fuy + nz*Fuz;
            double C_w = nx*Fwx + ny*Fwy + nz*Fwz;
            // s = B/m^3 when m > eps else 0 (original dropped the term there)
            double s = (m > 1e-12) ? ((B*inv)*inv)*inv : 0.0;
            double gnu = (A_u*inv - s*C_u) * invLn;
            double gnw = (A_w*inv - s*C_w) * invLn;
            gu = (gu + 0.01*gnu) * inv_denom;   // mask=1, masked-mean scaling
            gw = (gw + 0.01*gnw) * inv_denom;
            // Adagrad(lr=0.2, lr_decay=0.1)
            su += gu*gu; sw += gw*gw;
            double clr = clrtab[it];
            du -= clr * gu / (sqrt(su) + 1e-10);
            dw -= clr * gw / (sqrt(sw) + 1e-10);
        }
        u += du * alpha; w += dw * alpha;
        alpha *= 0.5;
    }
    out[NP + 2*p + 0] = (float)u;
    out[NP + 2*p + 1] = (float)w;
}

// ---------------------------------------------------------------------------
extern "C" void kernel_launch(void* const* d_in, const int* in_sizes, int n_in,
                              void* d_out, int out_size, void* d_ws, size_t ws_size,
                              hipStream_t stream) {
    const float* qV = (const float*)d_in[0];   // query_V [1,8192,3]
    const float* qN = (const float*)d_in[1];   // query_N [1,8192,3]
    const float* mV = (const float*)d_in[2];   // mesh_V  [16384,3]
    const int*   mF = (const int*)d_in[3];     // mesh_F  [16384,3] int32
    const float* mN = (const float*)d_in[4];   // mesh_N  [16384,3]
    float* out = (float*)d_out;                // fidx | vw | outlier_mask

    double* ctr      = (double*)d_ws;          // NF*4 doubles (cx,cy,cz,|c|^2)
    double* denom    = ctr + (size_t)NF*4;     // 1 double
    double* clrtab   = denom + 1;              // 50 doubles
    int*    fidx_ws  = (int*)(clrtab + 50);    // NP ints
    int*    valid_ws = fidx_ws + NP;           // NP ints

    hipLaunchKernelGGL(k_centers, dim3(NF/256), dim3(256), 0, stream, mV, mF, ctr, clrtab);
    hipLaunchKernelGGL(k_knn,     dim3(NP/GQ),  dim3(256), 0, stream, qV, ctr, out, fidx_ws, valid_ws);
    hipLaunchKernelGGL(k_denom,   dim3(1),      dim3(256), 0, stream, valid_ws, denom);
    hipLaunchKernelGGL(k_opt,     dim3(NP/256), dim3(256), 0, stream,
                       qV, qN, mV, mF, mN, fidx_ws, valid_ws, denom, clrtab, out);
}

// Round 4
// 106.591 us; speedup vs baseline: 1.4029x; 1.0436x over previous
//
#include <hip/hip_runtime.h>
#include <math.h>

#define NP 8192
#define NF 16384
#define GQ 16

// ---------------------------------------------------------------------------
// K0: face centers in f64 + |c|^2 (np: c=(v0+v1+v2)/3), plus Adagrad clr table
// ---------------------------------------------------------------------------
__global__ __launch_bounds__(256) void k_centers(const float* __restrict__ mV,
                                                 const int* __restrict__ mF,
                                                 double* __restrict__ ctr,
                                                 double* __restrict__ clrtab) {
    if (blockIdx.x == 0 && threadIdx.x < 50) {
        clrtab[threadIdx.x] = 0.2 / (1.0 + (double)threadIdx.x * 0.1);
    }
    int f = blockIdx.x * 256 + threadIdx.x;
    if (f >= NF) return;
    int i0 = mF[3*f+0], i1 = mF[3*f+1], i2 = mF[3*f+2];
    double cx = ((double)mV[3*i0+0] + (double)mV[3*i1+0] + (double)mV[3*i2+0]) / 3.0;
    double cy = ((double)mV[3*i0+1] + (double)mV[3*i1+1] + (double)mV[3*i2+1]) / 3.0;
    double cz = ((double)mV[3*i0+2] + (double)mV[3*i1+2] + (double)mV[3*i2+2]) / 3.0;
    ctr[4*f+0] = cx; ctr[4*f+1] = cy; ctr[4*f+2] = cz;
    ctr[4*f+3] = cx*cx + cy*cy + cz*cz;
}

// ---------------------------------------------------------------------------
// K1: brute-force 1-NN. Per-pair key = |c|^2 - 2 q.c (monotone in d2).
// Winner's true d2 recomputed with np's association (qq - 2 dot) + cc for the
// outlier test. Lexicographic (key,idx) reduction == jnp.argmin tie-break.
// GQ=16: halves L2 traffic vs GQ=8, 2 waves/SIMD residency.
// ---------------------------------------------------------------------------
__global__ __launch_bounds__(256) void k_knn(const float* __restrict__ qV,
                                             const double* __restrict__ ctr,
                                             float* __restrict__ out,
                                             int* __restrict__ fidx_ws,
                                             int* __restrict__ valid_ws) {
    int pbase = blockIdx.x * GQ;
    double qx[GQ], qy[GQ], qz[GQ];
    #pragma unroll
    for (int g = 0; g < GQ; ++g) {
        int p = pbase + g;
        qx[g] = (double)qV[3*p+0];
        qy[g] = (double)qV[3*p+1];
        qz[g] = (double)qV[3*p+2];
    }
    double best[GQ]; int bidx[GQ];
    #pragma unroll
    for (int g = 0; g < GQ; ++g) { best[g] = 1e300; bidx[g] = 0x7fffffff; }

    const double4* ctr4 = (const double4*)ctr;
    #pragma unroll 2
    for (int f = threadIdx.x; f < NF; f += 256) {
        double4 c = ctr4[f];
        #pragma unroll
        for (int g = 0; g < GQ; ++g) {
            double dot = qx[g]*c.x + qy[g]*c.y + qz[g]*c.z;
            double key = c.w - 2.0*dot;
            if (key < best[g]) { best[g] = key; bidx[g] = f; }
        }
    }
    // wave (64-lane) reduction, lexicographic (key, idx)
    #pragma unroll
    for (int off = 32; off > 0; off >>= 1) {
        #pragma unroll
        for (int g = 0; g < GQ; ++g) {
            double ov = __shfl_down(best[g], off);
            int    oi = __shfl_down(bidx[g], off);
            if (ov < best[g] || (ov == best[g] && oi < bidx[g])) { best[g] = ov; bidx[g] = oi; }
        }
    }
    __shared__ double sv[4][GQ];
    __shared__ int    si[4][GQ];
    int wid = threadIdx.x >> 6, lane = threadIdx.x & 63;
    if (lane == 0) {
        #pragma unroll
        for (int g = 0; g < GQ; ++g) { sv[wid][g] = best[g]; si[wid][g] = bidx[g]; }
    }
    __syncthreads();
    if (threadIdx.x == 0) {
        for (int g = 0; g < GQ; ++g) {
            double bv = sv[0][g]; int bi = si[0][g];
            for (int w2 = 1; w2 < 4; ++w2) {
                double ov = sv[w2][g]; int oi = si[w2][g];
                if (ov < bv || (ov == bv && oi < bi)) { bv = ov; bi = oi; }
            }
            int p = pbase + g;
            // exact np d2 for the winning face
            double4 c = ctr4[bi];
            double dot = qx[g]*c.x + qy[g]*c.y + qz[g]*c.z;
            double qq  = qx[g]*qx[g] + qy[g]*qy[g] + qz[g]*qz[g];
            double d2  = (qq - 2.0*dot) + c.w;
            int outlier = (d2 > 0.1) ? 1 : 0;
            fidx_ws[p]  = bi;
            valid_ws[p] = 1 - outlier;
            out[p]          = (float)bi;              // output 0: spt_fidx
            out[3*NP + p]   = outlier ? 1.0f : 0.0f;  // output 2: outlier_mask
        }
    }
}

// ---------------------------------------------------------------------------
// K2: denom = max(#valid, 1)
// ---------------------------------------------------------------------------
__global__ __launch_bounds__(256) void k_denom(const int* __restrict__ valid_ws,
                                               double* __restrict__ denom) {
    __shared__ int s[256];
    int acc = 0;
    for (int i = threadIdx.x; i < NP; i += 256) acc += valid_ws[i];
    s[threadIdx.x] = acc;
    __syncthreads();
    for (int off = 128; off > 0; off >>= 1) {
        if (threadIdx.x < off) s[threadIdx.x] += s[threadIdx.x + off];
        __syncthreads();
    }
    if (threadIdx.x == 0) {
        double d = (double)s[0];
        denom[0] = d > 1.0 ? d : 1.0;
    }
}

// ---------------------------------------------------------------------------
// K3: per-point 2x50-step Adagrad, f64, latency-minimized:
//   - rsqrt(x) replaces sqrt-then-div for invLv, inv(m), invLn (3 long-op
//     pairs -> 3 single long ops on the dependent chain; <=2 ulp each)
//   - m>1e-12 clamp expressed as m2>1e-24 (equivalent, avoids computing m)
//   - Adagrad tail keeps exact sqrt(s)+1e-10 then divide (eps semantics)
// ---------------------------------------------------------------------------
__global__ __launch_bounds__(256) void k_opt(const float* __restrict__ qV,
                                             const float* __restrict__ qN,
                                             const float* __restrict__ mV,
                                             const int* __restrict__ mF,
                                             const float* __restrict__ mN,
                                             const int* __restrict__ fidx_ws,
                                             const int* __restrict__ valid_ws,
                                             const double* __restrict__ denomp,
                                             const double* __restrict__ clrtab,
                                             float* __restrict__ out) {
    int p = blockIdx.x * 256 + threadIdx.x;
    if (p >= NP) return;
    const float third = (float)(1.0/3.0);
    if (!valid_ws[p]) {            // outlier: keeps init barycentric coords
        out[NP + 2*p + 0] = third;
        out[NP + 2*p + 1] = third;
        return;
    }
    double inv_denom = 1.0 / denomp[0];
    int f = fidx_ws[p];
    int i0 = mF[3*f+0], i1 = mF[3*f+1], i2 = mF[3*f+2];

    double V0x = mV[3*i0+0], V0y = mV[3*i0+1], V0z = mV[3*i0+2];
    double V1x = mV[3*i1+0], V1y = mV[3*i1+1], V1z = mV[3*i1+2];
    double V2x = mV[3*i2+0], V2y = mV[3*i2+1], V2z = mV[3*i2+2];
    double N0x = mN[3*i0+0], N0y = mN[3*i0+1], N0z = mN[3*i0+2];
    double N1x = mN[3*i1+0], N1y = mN[3*i1+1], N1z = mN[3*i1+2];
    double N2x = mN[3*i2+0], N2y = mN[3*i2+1], N2z = mN[3*i2+2];
    double qx  = qV[3*p+0],  qy  = qV[3*p+1],  qz  = qV[3*p+2];
    double qnx = qN[3*p+0],  qny = qN[3*p+1],  qnz = qN[3*p+2];

    double Eux = V0x - V2x, Euy = V0y - V2y, Euz = V0z - V2z;  // dcV/du
    double Ewx = V1x - V2x, Ewy = V1y - V2y, Ewz = V1z - V2z;  // dcV/dw
    double Fux = N0x - N2x, Fuy = N0y - N2y, Fuz = N0z - N2z;  // dn_raw/du
    double Fwx = N1x - N2x, Fwy = N1y - N2y, Fwz = N1z - N2z;  // dn_raw/dw
    double Kx  = V2x - qx,  Ky  = V2y - qy,  Kz  = V2z - qz;   // cv - q at uu=ww=0

    double u = 1.0/3.0, w = 1.0/3.0;
    double alpha = 1.0;
    for (int outer = 0; outer < 2; ++outer) {
        double du = 0.0, dw = 0.0, su = 0.0, sw = 0.0;
        for (int it = 0; it < 50; ++it) {
            double uu = u + du, ww = w + dw;
            // position term: rv = cv - q = uu*Eu + ww*Ew + K
            double rvx = uu*Eux + ww*Ewx + Kx;
            double rvy = uu*Euy + ww*Ewy + Ky;
            double rvz = uu*Euz + ww*Ewz + Kz;
            double L2v = rvx*rvx + rvy*rvy + rvz*rvz;
            double invLv = rsqrt(L2v);
            double gu = (rvx*Eux + rvy*Euy + rvz*Euz) * invLv;
            double gw = (rvx*Ewx + rvy*Ewy + rvz*Ewz) * invLv;
            // normal term: n = uu*Fu + ww*Fw + N2
            double nx = uu*Fux + ww*Fwx + N2x;
            double ny = uu*Fuy + ww*Fwy + N2y;
            double nz = uu*Fuz + ww*Fwz + N2z;
            double m2 = nx*nx + ny*ny + nz*nz;
            bool   mok = (m2 > 1e-24);          // <=> m > 1e-12
            double inv = mok ? rsqrt(m2) : 1e12; // 1/max(m,1e-12)
            double hx = nx*inv, hy = ny*inv, hz = nz*inv;
            double rnx = hx - qnx, rny = hy - qny, rnz = hz - qnz;
            double L2n = rnx*rnx + rny*rny + rnz*rnz;
            double invLn = rsqrt(L2n);
            double A_u = rnx*Fux + rny*Fuy + rnz*Fuz;
            double A_w = rnx*Fwx + rny*Fwy + rnz*Fwz;
            double B   = rnx*nx + rny*ny + rnz*nz;
            double C_u = nx*Fux + ny*Fuy + nz*Fuz;
            double C_w = nx*Fwx + ny*Fwy + nz*Fwz;
            // s = B/m^3 when m > eps else 0 (original dropped the term there)
            double s = mok ? ((B*inv)*inv)*inv : 0.0;
            double gnu = (A_u*inv - s*C_u) * invLn;
            double gnw = (A_w*inv - s*C_w) * invLn;
            gu = (gu + 0.01*gnu) * inv_denom;   // mask=1, masked-mean scaling
            gw = (gw + 0.01*gnw) * inv_denom;
            // Adagrad(lr=0.2, lr_decay=0.1)
            su += gu*gu; sw += gw*gw;
            double clr = clrtab[it];
            du -= clr * gu / (sqrt(su) + 1e-10);
            dw -= clr * gw / (sqrt(sw) + 1e-10);
        }
        u += du * alpha; w += dw * alpha;
        alpha *= 0.5;
    }
    out[NP + 2*p + 0] = (float)u;
    out[NP + 2*p + 1] = (float)w;
}

// ---------------------------------------------------------------------------
extern "C" void kernel_launch(void* const* d_in, const int* in_sizes, int n_in,
                              void* d_out, int out_size, void* d_ws, size_t ws_size,
                              hipStream_t stream) {
    const float* qV = (const float*)d_in[0];   // query_V [1,8192,3]
    const float* qN = (const float*)d_in[1];   // query_N [1,8192,3]
    const float* mV = (const float*)d_in[2];   // mesh_V  [16384,3]
    const int*   mF = (const int*)d_in[3];     // mesh_F  [16384,3] int32
    const float* mN = (const float*)d_in[4];   // mesh_N  [16384,3]
    float* out = (float*)d_out;                // fidx | vw | outlier_mask

    double* ctr      = (double*)d_ws;          // NF*4 doubles (cx,cy,cz,|c|^2)
    double* denom    = ctr + (size_t)NF*4;     // 1 double
    double* clrtab   = denom + 1;              // 50 doubles
    int*    fidx_ws  = (int*)(clrtab + 50);    // NP ints
    int*    valid_ws = fidx_ws + NP;           // NP ints

    hipLaunchKernelGGL(k_centers, dim3(NF/256), dim3(256), 0, stream, mV, mF, ctr, clrtab);
    hipLaunchKernelGGL(k_knn,     dim3(NP/GQ),  dim3(256), 0, stream, qV, ctr, out, fidx_ws, valid_ws);
    hipLaunchKernelGGL(k_denom,   dim3(1),      dim3(256), 0, stream, valid_ws, denom);
    hipLaunchKernelGGL(k_opt,     dim3(NP/256), dim3(256), 0, stream,
                       qV, qN, mV, mF, mN, fidx_ws, valid_ws, denom, clrtab, out);
}